// Round 1
// baseline (1089.750 us; speedup 1.0000x reference)
//
#include <hip/hip_runtime.h>
#include <hip/hip_bf16.h>
#include <math.h>

constexpr int BB = 2;
constexpr int LL = 1024;
constexpr int DD = 768;
constexpr int HH = 12;
constexpr int NEz = 42;
constexpr int MM = 8;
constexpr int NPp = 1722;
constexpr int CC = 97;
constexpr int FF = 256;
constexpr int PAIRS = NEz * NEz;   // 1764

// ---------------- K1: seqW[b,l,k] = sum_d seq[b,l,d] * W_lin[d,k] ----------------
__global__ void k_seqw(const float* __restrict__ seq, const float* __restrict__ Wl,
                       float* __restrict__ seqW) {
    int bl = blockIdx.x;            // b*LL + l
    int lane = threadIdx.x;         // 64 threads = 1 wave
    const float* row = seq + (size_t)bl * DD;
    float a0 = 0.f, a1 = 0.f, a2 = 0.f;
    for (int d = lane; d < DD; d += 64) {
        float v = row[d];
        a0 += v * Wl[d * 3 + 0];
        a1 += v * Wl[d * 3 + 1];
        a2 += v * Wl[d * 3 + 2];
    }
    for (int off = 32; off; off >>= 1) {
        a0 += __shfl_down(a0, off);
        a1 += __shfl_down(a1, off);
        a2 += __shfl_down(a2, off);
    }
    if (lane == 0) {
        seqW[bl * 3 + 0] = a0;
        seqW[bl * 3 + 1] = a1;
        seqW[bl * 3 + 2] = a2;
    }
}

// ---------------- K2: ent_emb = masked logsumexp over M mentions ----------------
__global__ void k_ent_emb(const float* __restrict__ seq, const int* __restrict__ midx,
                          const int* __restrict__ mmask, float* __restrict__ ent_emb) {
    int be = blockIdx.x;            // b*NE + e
    int b = be / NEz;
    int tid = threadIdx.x;          // 256
    int idx[MM], msk[MM];
#pragma unroll
    for (int m = 0; m < MM; ++m) {
        idx[m] = midx[be * MM + m];
        msk[m] = mmask[be * MM + m];
    }
    const float* sb = seq + (size_t)b * LL * DD;
    for (int d = tid; d < DD; d += 256) {
        float v[MM];
        float mx = -1e30f;
#pragma unroll
        for (int m = 0; m < MM; ++m) {
            v[m] = msk[m] ? sb[(size_t)idx[m] * DD + d] : -1e30f;
            mx = fmaxf(mx, v[m]);
        }
        float s = 0.f;
#pragma unroll
        for (int m = 0; m < MM; ++m) s += expf(v[m] - mx);
        ent_emb[(size_t)be * DD + d] = mx + logf(s);
    }
}

// ---------------- K3: ent_att[b,e,h,:] = sum_m mask*att[b,h,idx,:] / msum --------
__global__ void k_ent_att(const float* __restrict__ att, const int* __restrict__ midx,
                          const int* __restrict__ mmask, float* __restrict__ ea) {
    int beh = blockIdx.x;           // (b*NE+e)*H + h
    int h = beh % HH;
    int be = beh / HH;
    int b = be / NEz;
    int tid = threadIdx.x;          // 256
    int idx[MM], msk[MM];
    float msum = 0.f;
#pragma unroll
    for (int m = 0; m < MM; ++m) {
        idx[m] = midx[be * MM + m];
        msk[m] = mmask[be * MM + m];
        msum += (float)msk[m];
    }
    float inv = 1.f / msum;
    const float* ab = att + ((size_t)b * HH + h) * LL * LL;
#pragma unroll
    for (int li = 0; li < 4; ++li) {
        int l = tid + li * 256;
        float acc = 0.f;
#pragma unroll
        for (int m = 0; m < MM; ++m)
            if (msk[m]) acc += ab[(size_t)idx[m] * LL + l];
        ea[(size_t)beh * LL + l] = acc * inv;
    }
}

// ---------------- K4: per pair: ht_att -> normalize -> z -> attn_map row ---------
__global__ void k_pair(const float* __restrict__ ea, const float* __restrict__ seqW,
                       const float* __restrict__ Wseg, const float* __restrict__ bseg,
                       const float* __restrict__ blin, float* __restrict__ am) {
    int bp = blockIdx.x;            // b*PAIRS + p
    int b = bp / PAIRS;
    int p = bp % PAIRS;
    int e1 = p / NEz, e2 = p % NEz;
    int tid = threadIdx.x;          // 256
    int lane = tid & 63, wid = tid >> 6;

    const float* ea1 = ea + ((size_t)(b * NEz + e1)) * HH * LL;
    const float* ea2 = ea + ((size_t)(b * NEz + e2)) * HH * LL;

    float myht[4];
    float lsum = 0.f;
#pragma unroll
    for (int li = 0; li < 4; ++li) {
        int l = tid + li * 256;
        float acc = 0.f;
#pragma unroll
        for (int h = 0; h < HH; ++h) acc += ea1[h * LL + l] * ea2[h * LL + l];
        acc *= (1.0f / HH);
        myht[li] = acc;
        lsum += acc;
    }
    __shared__ float red4[4];
    __shared__ float redz[3][4];
    for (int off = 32; off; off >>= 1) lsum += __shfl_down(lsum, off);
    if (lane == 0) red4[wid] = lsum;
    __syncthreads();
    float s = red4[0] + red4[1] + red4[2] + red4[3];
    float scale = 1.f / (s + 1e-5f);

    float z0 = 0.f, z1 = 0.f, z2 = 0.f;
#pragma unroll
    for (int li = 0; li < 4; ++li) {
        int l = tid + li * 256;
        float w = myht[li] * scale;
        const float* sw = seqW + ((size_t)b * LL + l) * 3;
        z0 += w * sw[0];
        z1 += w * sw[1];
        z2 += w * sw[2];
    }
    for (int off = 32; off; off >>= 1) {
        z0 += __shfl_down(z0, off);
        z1 += __shfl_down(z1, off);
        z2 += __shfl_down(z2, off);
    }
    if (lane == 0) { redz[0][wid] = z0; redz[1][wid] = z1; redz[2][wid] = z2; }
    __syncthreads();
    float ai0 = redz[0][0] + redz[0][1] + redz[0][2] + redz[0][3] + blin[0];
    float ai1 = redz[1][0] + redz[1][1] + redz[1][2] + redz[1][3] + blin[1];
    float ai2 = redz[2][0] + redz[2][1] + redz[2][2] + redz[2][3] + blin[2];
    float val = ai0 * Wseg[0 * FF + tid] + ai1 * Wseg[1 * FF + tid] +
                ai2 * Wseg[2 * FF + tid] + bseg[tid];
    am[(size_t)bp * FF + tid] = fmaxf(val, 0.f);
}

// ---------------- K5: EWh/EWt = ent_emb @ W_head/tail + bias ---------------------
__global__ void k_ew(const float* __restrict__ ent_emb, const float* __restrict__ Wh,
                     const float* __restrict__ bh, const float* __restrict__ Wt,
                     const float* __restrict__ bt, float* __restrict__ EWh,
                     float* __restrict__ EWt) {
    int be = blockIdx.x;
    int tid = threadIdx.x;          // 256
    __shared__ float e[DD];
    for (int d = tid; d < DD; d += 256) e[d] = ent_emb[(size_t)be * DD + d];
    __syncthreads();
    float ah = bh[tid], at = bt[tid];
    for (int d = 0; d < DD; ++d) {
        float ev = e[d];
        ah += ev * Wh[d * FF + tid];
        at += ev * Wt[d * FF + tid];
    }
    EWh[(size_t)be * FF + tid] = ah;
    EWt[(size_t)be * FF + tid] = at;
}

// ---------------- K6: logits[b,p,o] = hsv^T W_bil[o] tsv + b_bil -----------------
constexpr int PT = 16;
constexpr int PTILES = (NPp + PT - 1) / PT;  // 108
constexpr int OS = 4;

__launch_bounds__(256)
__global__ void k_bil(const float* __restrict__ EWh, const float* __restrict__ EWt,
                      const float* __restrict__ am, const int* __restrict__ hts,
                      const float* __restrict__ Wb, const float* __restrict__ bbil,
                      float* __restrict__ out) {
    int bt_ = blockIdx.x;           // b*PTILES + pt
    int b = bt_ / PTILES;
    int p0 = (bt_ % PTILES) * PT;
    int os = blockIdx.y;
    int o_begin = (os == 0) ? 0 : 25 + (os - 1) * 24;
    int o_end = (os == 0) ? 25 : o_begin + 24;
    int tid = threadIdx.x;          // 256
    int lane = tid & 63, wid = tid >> 6;

    __shared__ float hsvT[FF][PT];  // [i][p]
    __shared__ float tsv[PT][FF];   // [p][j]
    __shared__ float red[PT][4];

    for (int p = 0; p < PT; ++p) {
        int pp = p0 + p;
        float hv = 0.f, tv = 0.f;
        if (pp < NPp) {
            int e1 = hts[(b * NPp + pp) * 2 + 0];
            int e2 = hts[(b * NPp + pp) * 2 + 1];
            float htv = am[((size_t)b * PAIRS + e1 * NEz + e2) * FF + tid];
            hv = tanhf(EWh[(size_t)(b * NEz + e1) * FF + tid] + htv);
            tv = tanhf(EWt[(size_t)(b * NEz + e2) * FF + tid] + htv);
        }
        hsvT[tid][p] = hv;
        tsv[p][tid] = tv;
    }
    __syncthreads();

    for (int o = o_begin; o < o_end; ++o) {
        const float* w = Wb + (size_t)o * FF * FF + tid;
        float acc[PT];
#pragma unroll
        for (int p = 0; p < PT; ++p) acc[p] = 0.f;
        for (int i = 0; i < FF; i += 4) {
            float w4[4];
            w4[0] = w[(i + 0) * FF];
            w4[1] = w[(i + 1) * FF];
            w4[2] = w[(i + 2) * FF];
            w4[3] = w[(i + 3) * FF];
#pragma unroll
            for (int ii = 0; ii < 4; ++ii) {
                float wv = w4[ii];
#pragma unroll
                for (int p = 0; p < PT; p += 4) {
                    const float4 h = *(const float4*)&hsvT[i + ii][p];
                    acc[p + 0] += h.x * wv;
                    acc[p + 1] += h.y * wv;
                    acc[p + 2] += h.z * wv;
                    acc[p + 3] += h.w * wv;
                }
            }
        }
#pragma unroll
        for (int p = 0; p < PT; ++p) {
            float v = acc[p] * tsv[p][tid];
            for (int off = 32; off; off >>= 1) v += __shfl_down(v, off);
            if (lane == 0) red[p][wid] = v;
        }
        __syncthreads();
        if (tid < PT) {
            int pp = p0 + tid;
            if (pp < NPp) {
                float r = red[tid][0] + red[tid][1] + red[tid][2] + red[tid][3] + bbil[o];
                out[(size_t)(b * NPp + pp) * CC + o] = r;
            }
        }
        __syncthreads();
    }
}

extern "C" void kernel_launch(void* const* d_in, const int* in_sizes, int n_in,
                              void* d_out, int out_size, void* d_ws, size_t ws_size,
                              hipStream_t stream) {
    const float* seq   = (const float*)d_in[0];
    const float* att   = (const float*)d_in[1];
    const int*   midx  = (const int*)d_in[2];
    const int*   mmask = (const int*)d_in[3];
    const int*   hts   = (const int*)d_in[4];
    const float* Wlin  = (const float*)d_in[5];
    const float* blin  = (const float*)d_in[6];
    const float* Wseg  = (const float*)d_in[7];
    const float* bseg  = (const float*)d_in[8];
    const float* Whead = (const float*)d_in[9];
    const float* bhead = (const float*)d_in[10];
    const float* Wtail = (const float*)d_in[11];
    const float* btail = (const float*)d_in[12];
    const float* Wbil  = (const float*)d_in[13];
    const float* bbil  = (const float*)d_in[14];
    float* out = (float*)d_out;

    float* ws = (float*)d_ws;
    float* ent_emb = ws;                          // B*NE*D      = 64512
    float* ea      = ent_emb + BB * NEz * DD;     // B*NE*H*L    = 1032192
    float* seqW    = ea + (size_t)BB * NEz * HH * LL;  // B*L*3 = 6144
    float* am      = seqW + BB * LL * 3;          // B*PAIRS*F2  = 903168
    float* EWh     = am + (size_t)BB * PAIRS * FF;     // B*NE*F2
    float* EWt     = EWh + BB * NEz * FF;

    k_seqw<<<BB * LL, 64, 0, stream>>>(seq, Wlin, seqW);
    k_ent_emb<<<BB * NEz, 256, 0, stream>>>(seq, midx, mmask, ent_emb);
    k_ent_att<<<BB * NEz * HH, 256, 0, stream>>>(att, midx, mmask, ea);
    k_pair<<<BB * PAIRS, 256, 0, stream>>>(ea, seqW, Wseg, bseg, blin, am);
    k_ew<<<BB * NEz, 256, 0, stream>>>(ent_emb, Whead, bhead, Wtail, btail, EWh, EWt);
    k_bil<<<dim3(BB * PTILES, OS), 256, 0, stream>>>(EWh, EWt, am, hts, Wbil, bbil, out);
}

// Round 2
// 195.140 us; speedup vs baseline: 5.5845x; 5.5845x over previous
//
#include <hip/hip_runtime.h>
#include <hip/hip_bf16.h>
#include <math.h>

constexpr int BB = 2;
constexpr int LL = 1024;
constexpr int DD = 768;
constexpr int HH = 12;
constexpr int NEz = 42;
constexpr int MM = 8;
constexpr int NPp = 1722;
constexpr int CC = 97;
constexpr int FF = 256;
constexpr int PAIRS = NEz * NEz;   // 1764
constexpr int TOTAL = BB * NPp;    // 3444
constexpr int PT64 = (TOTAL + 63) / 64;  // 54

typedef float f32x4 __attribute__((ext_vector_type(4)));
typedef short bf16x8 __attribute__((ext_vector_type(8)));

// ---------------- K1: seqW[b,l,k] = sum_d seq[b,l,d] * W_lin[d,k] ----------------
__global__ void k_seqw(const float* __restrict__ seq, const float* __restrict__ Wl,
                       float* __restrict__ seqW) {
    int bl = blockIdx.x;
    int lane = threadIdx.x;
    const float* row = seq + (size_t)bl * DD;
    float a0 = 0.f, a1 = 0.f, a2 = 0.f;
    for (int d = lane; d < DD; d += 64) {
        float v = row[d];
        a0 += v * Wl[d * 3 + 0];
        a1 += v * Wl[d * 3 + 1];
        a2 += v * Wl[d * 3 + 2];
    }
    for (int off = 32; off; off >>= 1) {
        a0 += __shfl_down(a0, off);
        a1 += __shfl_down(a1, off);
        a2 += __shfl_down(a2, off);
    }
    if (lane == 0) {
        seqW[bl * 3 + 0] = a0;
        seqW[bl * 3 + 1] = a1;
        seqW[bl * 3 + 2] = a2;
    }
}

// ---------------- K2: ent_emb = masked logsumexp over M mentions ----------------
__global__ void k_ent_emb(const float* __restrict__ seq, const int* __restrict__ midx,
                          const int* __restrict__ mmask, float* __restrict__ ent_emb) {
    int be = blockIdx.x;
    int b = be / NEz;
    int tid = threadIdx.x;
    int idx[MM], msk[MM];
#pragma unroll
    for (int m = 0; m < MM; ++m) {
        idx[m] = midx[be * MM + m];
        msk[m] = mmask[be * MM + m];
    }
    const float* sb = seq + (size_t)b * LL * DD;
    for (int d = tid; d < DD; d += 256) {
        float v[MM];
        float mx = -1e30f;
#pragma unroll
        for (int m = 0; m < MM; ++m) {
            v[m] = msk[m] ? sb[(size_t)idx[m] * DD + d] : -1e30f;
            mx = fmaxf(mx, v[m]);
        }
        float s = 0.f;
#pragma unroll
        for (int m = 0; m < MM; ++m) s += expf(v[m] - mx);
        ent_emb[(size_t)be * DD + d] = mx + logf(s);
    }
}

// ---------------- K3: ent_att ----------------
__global__ void k_ent_att(const float* __restrict__ att, const int* __restrict__ midx,
                          const int* __restrict__ mmask, float* __restrict__ ea) {
    int beh = blockIdx.x;
    int h = beh % HH;
    int be = beh / HH;
    int b = be / NEz;
    int tid = threadIdx.x;
    int idx[MM], msk[MM];
    float msum = 0.f;
#pragma unroll
    for (int m = 0; m < MM; ++m) {
        idx[m] = midx[be * MM + m];
        msk[m] = mmask[be * MM + m];
        msum += (float)msk[m];
    }
    float inv = 1.f / msum;
    const float* ab = att + ((size_t)b * HH + h) * LL * LL;
#pragma unroll
    for (int li = 0; li < 4; ++li) {
        int l = tid + li * 256;
        float acc = 0.f;
#pragma unroll
        for (int m = 0; m < MM; ++m)
            if (msk[m]) acc += ab[(size_t)idx[m] * LL + l];
        ea[(size_t)beh * LL + l] = acc * inv;
    }
}

// ---------------- K4: per pair: ht_att -> normalize -> z -> attn_map row ---------
__global__ void k_pair(const float* __restrict__ ea, const float* __restrict__ seqW,
                       const float* __restrict__ Wseg, const float* __restrict__ bseg,
                       const float* __restrict__ blin, float* __restrict__ am) {
    int bp = blockIdx.x;
    int b = bp / PAIRS;
    int p = bp % PAIRS;
    int e1 = p / NEz, e2 = p % NEz;
    int tid = threadIdx.x;
    int lane = tid & 63, wid = tid >> 6;

    const float* ea1 = ea + ((size_t)(b * NEz + e1)) * HH * LL;
    const float* ea2 = ea + ((size_t)(b * NEz + e2)) * HH * LL;

    float myht[4];
    float lsum = 0.f;
#pragma unroll
    for (int li = 0; li < 4; ++li) {
        int l = tid + li * 256;
        float acc = 0.f;
#pragma unroll
        for (int h = 0; h < HH; ++h) acc += ea1[h * LL + l] * ea2[h * LL + l];
        acc *= (1.0f / HH);
        myht[li] = acc;
        lsum += acc;
    }
    __shared__ float red4[4];
    __shared__ float redz[3][4];
    for (int off = 32; off; off >>= 1) lsum += __shfl_down(lsum, off);
    if (lane == 0) red4[wid] = lsum;
    __syncthreads();
    float s = red4[0] + red4[1] + red4[2] + red4[3];
    float scale = 1.f / (s + 1e-5f);

    float z0 = 0.f, z1 = 0.f, z2 = 0.f;
#pragma unroll
    for (int li = 0; li < 4; ++li) {
        int l = tid + li * 256;
        float w = myht[li] * scale;
        const float* sw = seqW + ((size_t)b * LL + l) * 3;
        z0 += w * sw[0];
        z1 += w * sw[1];
        z2 += w * sw[2];
    }
    for (int off = 32; off; off >>= 1) {
        z0 += __shfl_down(z0, off);
        z1 += __shfl_down(z1, off);
        z2 += __shfl_down(z2, off);
    }
    if (lane == 0) { redz[0][wid] = z0; redz[1][wid] = z1; redz[2][wid] = z2; }
    __syncthreads();
    float ai0 = redz[0][0] + redz[0][1] + redz[0][2] + redz[0][3] + blin[0];
    float ai1 = redz[1][0] + redz[1][1] + redz[1][2] + redz[1][3] + blin[1];
    float ai2 = redz[2][0] + redz[2][1] + redz[2][2] + redz[2][3] + blin[2];
    float val = ai0 * Wseg[0 * FF + tid] + ai1 * Wseg[1 * FF + tid] +
                ai2 * Wseg[2 * FF + tid] + bseg[tid];
    am[(size_t)bp * FF + tid] = fmaxf(val, 0.f);
}

// ---------------- K5: EWh/EWt = ent_emb @ W_head/tail + bias ---------------------
__global__ void k_ew(const float* __restrict__ ent_emb, const float* __restrict__ Wh,
                     const float* __restrict__ bh, const float* __restrict__ Wt,
                     const float* __restrict__ bt, float* __restrict__ EWh,
                     float* __restrict__ EWt) {
    int be = blockIdx.x;
    int tid = threadIdx.x;
    __shared__ float e[DD];
    for (int d = tid; d < DD; d += 256) e[d] = ent_emb[(size_t)be * DD + d];
    __syncthreads();
    float ah = bh[tid], at = bt[tid];
    for (int d = 0; d < DD; ++d) {
        float ev = e[d];
        ah += ev * Wh[d * FF + tid];
        at += ev * Wt[d * FF + tid];
    }
    EWh[(size_t)be * FF + tid] = ah;
    EWt[(size_t)be * FF + tid] = at;
}

// ---------------- K6a: Wt[o][j][k] = bf16(W_bil[o][k][j]) (tiled transpose) ------
__global__ void k_wt(const float* __restrict__ Wb, __hip_bfloat16* __restrict__ Wt) {
    int o = blockIdx.y;
    int ti = blockIdx.x >> 2;   // k tile
    int tj = blockIdx.x & 3;    // j tile
    int tid = threadIdx.x;      // 256
    int lane = tid & 63, quad = tid >> 6;
    __shared__ float t64[64][65];
    const float* src = Wb + (size_t)o * FF * FF;
#pragma unroll 4
    for (int i = 0; i < 16; ++i) {
        int kr = quad * 16 + i;
        t64[kr][lane] = src[(size_t)(ti * 64 + kr) * FF + tj * 64 + lane];
    }
    __syncthreads();
    __hip_bfloat16* dst = Wt + (size_t)o * FF * FF;
#pragma unroll 4
    for (int i = 0; i < 16; ++i) {
        int jr = quad * 16 + i;
        dst[(size_t)(tj * 64 + jr) * FF + ti * 64 + lane] = __float2bfloat16(t64[lane][jr]);
    }
}

// ---------------- K6b: HSb/TSb = bf16(tanh(EW + htv)) ----------------------------
__global__ void k_prep(const float* __restrict__ EWh, const float* __restrict__ EWt,
                       const float* __restrict__ am, const int* __restrict__ hts,
                       __hip_bfloat16* __restrict__ HSb, __hip_bfloat16* __restrict__ TSb) {
    int bp = blockIdx.x;     // 0..TOTAL-1
    int b = bp / NPp;
    int t = threadIdx.x;     // 256
    int e1 = hts[bp * 2 + 0];
    int e2 = hts[bp * 2 + 1];
    float htv = am[((size_t)b * PAIRS + e1 * NEz + e2) * FF + t];
    float hv = tanhf(EWh[(size_t)(b * NEz + e1) * FF + t] + htv);
    float tv = tanhf(EWt[(size_t)(b * NEz + e2) * FF + t] + htv);
    HSb[(size_t)bp * FF + t] = __float2bfloat16(hv);
    TSb[(size_t)bp * FF + t] = __float2bfloat16(tv);
}

// ---------------- K6c: logits via MFMA -------------------------------------------
// block: 64 pairs x one o.  A = HSb tile (64x256), B = Wt[o] (256x256, [j][k]),
// T = A @ Wt[o]^T ... D[p,j] = sum_k HS[p,k]*W[o,k,j]; epilogue dot with TSb.
__launch_bounds__(256)
__global__ void k_bil_mfma(const __hip_bfloat16* __restrict__ HSb,
                           const __hip_bfloat16* __restrict__ TSb,
                           const __hip_bfloat16* __restrict__ Wtb,
                           const float* __restrict__ bbil,
                           float* __restrict__ out) {
    int p0 = blockIdx.x * 64;
    int o = blockIdx.y;
    int tid = threadIdx.x;          // 256 = 4 waves
    int lane = tid & 63, w = tid >> 6;
    int lg = lane >> 4;             // k-group 0..3
    int lr = lane & 15;             // row/col within fragment

    __shared__ __hip_bfloat16 Alds[64 * 256];   // 32 KB, swizzled
    __shared__ __hip_bfloat16 Blds[256 * 64];   // 32 KB, swizzled; reused for TS
    __shared__ float rowred[64][4];

    char* A_c = (char*)Alds;
    char* B_c = (char*)Blds;

    // ---- stage A tile (full K=256), XOR-swizzled ----
#pragma unroll
    for (int it = 0; it < 8; ++it) {
        int u = tid + it * 256;          // 2048 units of 16B
        int r = u >> 5;                  // row 0..63
        int k16 = u & 31;                // 16B unit within 512B row
        bf16x8 v = {0, 0, 0, 0, 0, 0, 0, 0};
        int p = p0 + r;
        if (p < TOTAL) v = *(const bf16x8*)(const void*)(HSb + (size_t)p * FF + k16 * 8);
        int byte = (r * 512 + k16 * 16) ^ ((r & 7) << 4);
        *(bf16x8*)(A_c + byte) = v;
    }

    f32x4 acc[4][4];
#pragma unroll
    for (int mi = 0; mi < 4; ++mi)
#pragma unroll
        for (int ni = 0; ni < 4; ++ni) acc[mi][ni] = (f32x4){0.f, 0.f, 0.f, 0.f};

    const __hip_bfloat16* Wo = Wtb + (size_t)o * FF * FF;

    for (int kc = 0; kc < 4; ++kc) {
        // ---- stage B chunk: Wt[o][n][kc*64 .. +64), swizzled ----
#pragma unroll
        for (int it = 0; it < 8; ++it) {
            int u = tid + it * 256;      // 2048 units of 16B
            int n = u >> 3;              // 0..255
            int k16 = u & 7;             // 16B unit within 128B row
            bf16x8 v = *(const bf16x8*)(const void*)(Wo + (size_t)n * FF + kc * 64 + k16 * 8);
            int byte = (n * 128 + k16 * 16) ^ ((n & 7) << 4);
            *(bf16x8*)(B_c + byte) = v;
        }
        __syncthreads();
#pragma unroll
        for (int ks = 0; ks < 2; ++ks) {
            bf16x8 af[4], bf[4];
#pragma unroll
            for (int mi = 0; mi < 4; ++mi) {
                int r = mi * 16 + lr;
                int k = kc * 64 + ks * 32 + lg * 8;
                int byte = (r * 512 + k * 2) ^ ((r & 7) << 4);
                af[mi] = *(const bf16x8*)(A_c + byte);
            }
#pragma unroll
            for (int ni = 0; ni < 4; ++ni) {
                int n = w * 64 + ni * 16 + lr;
                int k = ks * 32 + lg * 8;
                int byte = (n * 128 + k * 2) ^ ((n & 7) << 4);
                bf[ni] = *(const bf16x8*)(B_c + byte);
            }
#pragma unroll
            for (int mi = 0; mi < 4; ++mi)
#pragma unroll
                for (int ni = 0; ni < 4; ++ni)
                    acc[mi][ni] = __builtin_amdgcn_mfma_f32_16x16x32_bf16(
                        af[mi], bf[ni], acc[mi][ni], 0, 0, 0);
        }
        __syncthreads();
    }

    // ---- stage TS tile linearly into Blds ----
#pragma unroll
    for (int it = 0; it < 8; ++it) {
        int u = tid + it * 256;
        int r = u >> 5;
        int k16 = u & 31;
        bf16x8 v = {0, 0, 0, 0, 0, 0, 0, 0};
        int p = p0 + r;
        if (p < TOTAL) v = *(const bf16x8*)(const void*)(TSb + (size_t)p * FF + k16 * 8);
        *(bf16x8*)(B_c + r * 512 + k16 * 16) = v;
    }
    __syncthreads();

    const unsigned short* TSl = (const unsigned short*)Blds;
#pragma unroll
    for (int mi = 0; mi < 4; ++mi) {
#pragma unroll
        for (int reg = 0; reg < 4; ++reg) {
            int r = mi * 16 + lg * 4 + reg;
            float s = 0.f;
#pragma unroll
            for (int ni = 0; ni < 4; ++ni) {
                int c = w * 64 + ni * 16 + lr;
                float tsv = __uint_as_float((unsigned)TSl[r * 256 + c] << 16);
                s += acc[mi][ni][reg] * tsv;
            }
            s += __shfl_xor(s, 1);
            s += __shfl_xor(s, 2);
            s += __shfl_xor(s, 4);
            s += __shfl_xor(s, 8);
            if (lr == 0) rowred[r][w] = s;
        }
    }
    __syncthreads();
    if (tid < 64) {
        int p = p0 + tid;
        if (p < TOTAL)
            out[(size_t)p * CC + o] = rowred[tid][0] + rowred[tid][1] +
                                      rowred[tid][2] + rowred[tid][3] + bbil[o];
    }
}

extern "C" void kernel_launch(void* const* d_in, const int* in_sizes, int n_in,
                              void* d_out, int out_size, void* d_ws, size_t ws_size,
                              hipStream_t stream) {
    const float* seq   = (const float*)d_in[0];
    const float* att   = (const float*)d_in[1];
    const int*   midx  = (const int*)d_in[2];
    const int*   mmask = (const int*)d_in[3];
    const int*   hts   = (const int*)d_in[4];
    const float* Wlin  = (const float*)d_in[5];
    const float* blin  = (const float*)d_in[6];
    const float* Wseg  = (const float*)d_in[7];
    const float* bseg  = (const float*)d_in[8];
    const float* Whead = (const float*)d_in[9];
    const float* bhead = (const float*)d_in[10];
    const float* Wtail = (const float*)d_in[11];
    const float* btail = (const float*)d_in[12];
    const float* Wbil  = (const float*)d_in[13];
    const float* bbil  = (const float*)d_in[14];
    float* out = (float*)d_out;

    float* ws = (float*)d_ws;
    float* ent_emb = ws;                               // B*NE*D
    float* ea      = ent_emb + BB * NEz * DD;          // B*NE*H*L
    float* seqW    = ea + (size_t)BB * NEz * HH * LL;  // B*L*3
    float* am      = seqW + BB * LL * 3;               // B*PAIRS*F2
    float* EWh     = am + (size_t)BB * PAIRS * FF;     // B*NE*F2
    float* EWt     = EWh + BB * NEz * FF;              // B*NE*F2
    __hip_bfloat16* Wtb = (__hip_bfloat16*)(EWt + BB * NEz * FF);  // C*F2*F2
    __hip_bfloat16* HSb = Wtb + (size_t)CC * FF * FF;              // TOTAL*F2
    __hip_bfloat16* TSb = HSb + (size_t)TOTAL * FF;                // TOTAL*F2

    k_seqw<<<BB * LL, 64, 0, stream>>>(seq, Wlin, seqW);
    k_ent_emb<<<BB * NEz, 256, 0, stream>>>(seq, midx, mmask, ent_emb);
    k_ent_att<<<BB * NEz * HH, 256, 0, stream>>>(att, midx, mmask, ea);
    k_pair<<<BB * PAIRS, 256, 0, stream>>>(ea, seqW, Wseg, bseg, blin, am);
    k_ew<<<BB * NEz, 256, 0, stream>>>(ent_emb, Whead, bhead, Wtail, btail, EWh, EWt);
    k_wt<<<dim3(16, CC), 256, 0, stream>>>(Wbil, Wtb);
    k_prep<<<TOTAL, 256, 0, stream>>>(EWh, EWt, am, hts, HSb, TSb);
    k_bil_mfma<<<dim3(PT64, CC), 256, 0, stream>>>(HSb, TSb, Wtb, bbil, out);
}